// Round 7
// baseline (10219.045 us; speedup 1.0000x reference)
//
#include <hip/hip_runtime.h>
#include <hip/hip_bf16.h>
#include <math.h>

#define B_    2
#define S_    2048
#define H_    2048
#define NH_   16
#define NKV_  4
#define HD_   128
#define M_    (B_*S_)      // 4096
#define NKVH_ (NKV_*HD_)   // 512

__device__ __forceinline__ float bf2f(unsigned short u){
  unsigned int i = ((unsigned int)u) << 16; float f;
  __builtin_memcpy(&f, &i, 4); return f;
}
__device__ __forceinline__ unsigned short f2bf(float f){
  unsigned int i; __builtin_memcpy(&i, &f, 4);
  unsigned int r = (i + 0x7fffu + ((i >> 16) & 1u)) >> 16;
  return (unsigned short)r;
}

// ---------------- f32 -> bf16 bulk convert (float4 -> ushort4) ----------------
__global__ void k_f32_to_bf16(const float* __restrict__ in, unsigned short* __restrict__ out, int n4){
  int idx = blockIdx.x * blockDim.x + threadIdx.x;
  if (idx >= n4) return;
  float4 v = reinterpret_cast<const float4*>(in)[idx];
  ushort4 o; o.x = f2bf(v.x); o.y = f2bf(v.y); o.z = f2bf(v.z); o.w = f2bf(v.w);
  reinterpret_cast<ushort4*>(out)[idx] = o;
}

// ---------------- RoPE table: tab[s][i] = (cos, sin) of pos[s] * theta^(-i/64) ----------------
__global__ void k_rope_table(const int* __restrict__ pos, float2* __restrict__ tab){
  int idx = blockIdx.x * blockDim.x + threadIdx.x;
  if (idx >= S_ * 64) return;
  int s = idx >> 6, i = idx & 63;
  float p = (float)pos[s];                       // batch-0 positions (ref uses position_ids[0])
  float inv = expf(-(float)i * (13.815510557964274f / 64.0f));  // 1e6^(-i/64)
  float ang = p * inv;
  tab[idx] = make_float2(cosf(ang), sinf(ang));
}

// ---------------- RoPE in-place, Q: [4096][2048] bf16 ----------------
__global__ void k_rope_q(unsigned short* __restrict__ Q, const float2* __restrict__ tab){
  int idx = blockIdx.x * blockDim.x + threadIdx.x;  // 2,097,152
  int row = idx >> 9;            // 512 quads per row
  int col0 = (idx & 511) * 4;
  int s = row & (S_ - 1);
  int i0 = (col0 & (HD_ - 1)) >> 1;
  ushort4 v = reinterpret_cast<ushort4*>(Q)[idx];
  float2 t0 = tab[(s << 6) + i0], t1 = tab[(s << 6) + i0 + 1];
  float x0 = bf2f(v.x), x1 = bf2f(v.y), x2 = bf2f(v.z), x3 = bf2f(v.w);
  ushort4 o;
  o.x = f2bf(x0 * t0.x - x1 * t0.y);
  o.y = f2bf(x0 * t0.y + x1 * t0.x);
  o.z = f2bf(x2 * t1.x - x3 * t1.y);
  o.w = f2bf(x2 * t1.y + x3 * t1.x);
  reinterpret_cast<ushort4*>(Q)[idx] = o;
}

// ---- RoPE K: in-place bf16 for attention + UNROUNDED f32 rotation -> cache_k ----
__global__ void k_rope_k(unsigned short* __restrict__ Kw, const float2* __restrict__ tab,
                         float* __restrict__ cacheK){
  int idx = blockIdx.x * blockDim.x + threadIdx.x;  // 524,288
  int row = idx >> 7;            // 128 quads per row
  int col0 = (idx & 127) * 4;
  int s = row & (S_ - 1);
  int i0 = (col0 & (HD_ - 1)) >> 1;
  ushort4 v = reinterpret_cast<ushort4*>(Kw)[idx];
  float2 t0 = tab[(s << 6) + i0], t1 = tab[(s << 6) + i0 + 1];
  float x0 = bf2f(v.x), x1 = bf2f(v.y), x2 = bf2f(v.z), x3 = bf2f(v.w);
  float r0 = x0 * t0.x - x1 * t0.y;
  float r1 = x0 * t0.y + x1 * t0.x;
  float r2 = x2 * t1.x - x3 * t1.y;
  float r3 = x2 * t1.y + x3 * t1.x;
  ushort4 o; o.x = f2bf(r0); o.y = f2bf(r1); o.z = f2bf(r2); o.w = f2bf(r3);
  reinterpret_cast<ushort4*>(Kw)[idx] = o;
  float4 c; c.x = r0; c.y = r1; c.z = r2; c.w = r3;      // ref cache_k is f32 (no bf16 round)
  reinterpret_cast<float4*>(cacheK)[idx] = c;
}

// ---------------- V bf16 -> cache_v f32 (widen) ----------------
__global__ void k_v_to_f32(const unsigned short* __restrict__ in, float* __restrict__ out, int n4){
  int idx = blockIdx.x * blockDim.x + threadIdx.x;
  if (idx >= n4) return;
  ushort4 v = reinterpret_cast<const ushort4*>(in)[idx];
  float4 o; o.x = bf2f(v.x); o.y = bf2f(v.y); o.z = bf2f(v.z); o.w = bf2f(v.w);
  reinterpret_cast<float4*>(out)[idx] = o;
}

// ---------------- NAIVE GEMM: C = bf16(A) * bf16(W) + bias ----------------
// Cf != nullptr: write bf16-rounded value widened to f32 (final out, f32 buffer).
// else: write bf16 into Cb.
__global__ __launch_bounds__(256) void k_gemm_naive(
    const unsigned short* __restrict__ A,
    const float* __restrict__ W,
    const float* __restrict__ bias,
    unsigned short* __restrict__ Cb,
    float* __restrict__ Cf,
    int M, int N, int K)
{
  const int t = threadIdx.x;
  const int col = blockIdx.x * 64 + (t & 63);
  const int r0  = blockIdx.y * 64 + (t >> 6) * 16;
  float acc[16];
  #pragma unroll
  for (int i = 0; i < 16; i++) acc[i] = 0.f;
  for (int k = 0; k < K; ++k) {
    float wv = bf2f(f2bf(W[(size_t)k * N + col]));
    #pragma unroll
    for (int i = 0; i < 16; i++)
      acc[i] += bf2f(A[(size_t)(r0 + i) * K + k]) * wv;
  }
  float bv = bias ? bf2f(f2bf(bias[col])) : 0.f;
  #pragma unroll
  for (int i = 0; i < 16; i++) {
    float r = acc[i] + bv;
    size_t idx = (size_t)(r0 + i) * N + col;
    if (Cf) Cf[idx] = bf2f(f2bf(r));   // ref's out is bf16-valued, stored f32
    else    Cb[idx] = f2bf(r);
  }
}

// ---------------- NAIVE attention, flat 1D grid: wave -> (qrow, h, b) ----------------
// grid (S*NH*B/4) blocks x 256 threads (4 waves). Lane owns 2 channels.
__global__ __launch_bounds__(256) void k_attn_naive2(
    const unsigned short* __restrict__ Q,   // [4096][2048] bf16 (rope'd)
    const unsigned short* __restrict__ K,   // [4096][512]  bf16 (rope'd)
    const unsigned short* __restrict__ V,   // [4096][512]  bf16
    unsigned short* __restrict__ O)         // [4096][2048] bf16
{
  const int gid  = blockIdx.x * 4 + (threadIdx.x >> 6);   // 0 .. 65535
  const int lane = threadIdx.x & 63;
  const int qrow = gid & (S_ - 1);
  const int h    = (gid >> 11) & (NH_ - 1);
  const int b    = gid >> 15;
  const int kvh  = h >> 2;
  const float scale = 0.08838834764831845f;  // 1/sqrt(128)

  const unsigned short* qp = Q + (size_t)(b * S_ + qrow) * H_ + h * HD_ + lane * 2;
  ushort2 qv = *reinterpret_cast<const ushort2*>(qp);
  float q0 = bf2f(qv.x), q1 = bf2f(qv.y);

  float m = -1e30f, l = 0.f, o0 = 0.f, o1 = 0.f;
  const unsigned short* kb = K + (size_t)(b * S_) * NKVH_ + kvh * HD_ + lane * 2;
  const unsigned short* vb = V + (size_t)(b * S_) * NKVH_ + kvh * HD_ + lane * 2;

  for (int k = 0; k <= qrow; ++k) {
    ushort2 kv = *reinterpret_cast<const ushort2*>(kb + (size_t)k * NKVH_);
    float part = q0 * bf2f(kv.x) + q1 * bf2f(kv.y);
    #pragma unroll
    for (int msk = 1; msk < 64; msk <<= 1) part += __shfl_xor(part, msk);
    float s = part * scale;
    float mnew = fmaxf(m, s);
    float sc = __expf(m - mnew);
    float p = __expf(s - mnew);
    ushort2 vv = *reinterpret_cast<const ushort2*>(vb + (size_t)k * NKVH_);
    l = l * sc + p;
    o0 = o0 * sc + p * bf2f(vv.x);
    o1 = o1 * sc + p * bf2f(vv.y);
    m = mnew;
  }
  float inv = 1.0f / l;
  unsigned short* op = O + (size_t)(b * S_ + qrow) * H_ + h * HD_ + lane * 2;
  op[0] = f2bf(o0 * inv);
  op[1] = f2bf(o1 * inv);
}

// ---------------- launch ----------------
extern "C" void kernel_launch(void* const* d_in, const int* in_sizes, int n_in,
                              void* d_out, int out_size, void* d_ws, size_t ws_size,
                              hipStream_t stream) {
  const float* hidden = (const float*)d_in[0];
  const int*   pos    = (const int*)d_in[2];
  const float* wq     = (const float*)d_in[3];
  const float* bq     = (const float*)d_in[4];
  const float* wk     = (const float*)d_in[5];
  const float* bk     = (const float*)d_in[6];
  const float* wv     = (const float*)d_in[7];
  const float* bv     = (const float*)d_in[8];
  const float* wo     = (const float*)d_in[9];

  // d_out is FLOAT32 (mixed-dtype tuple -> "else float*" path):
  // [ out 8.4M f32 | cache_k 2.1M f32 | cache_v 2.1M f32 ]
  float* outF   = (float*)d_out;
  float* cacheK = outF + (size_t)M_ * H_;
  float* cacheV = cacheK + (size_t)M_ * NKVH_;

  char* w = (char*)d_ws;
  unsigned short* Xbf = (unsigned short*)w; w += (size_t)M_ * H_ * 2;      // 16.78 MB
  unsigned short* Qw  = (unsigned short*)w; w += (size_t)M_ * H_ * 2;      // 16.78 MB
  unsigned short* Kw  = (unsigned short*)w; w += (size_t)M_ * NKVH_ * 2;   //  4.19 MB
  unsigned short* Vw  = (unsigned short*)w; w += (size_t)M_ * NKVH_ * 2;   //  4.19 MB
  unsigned short* Ao  = (unsigned short*)w; w += (size_t)M_ * H_ * 2;      // 16.78 MB
  float2*         tab = (float2*)w;         w += (size_t)S_ * 64 * sizeof(float2); // 1 MB

  // 1. hidden f32 -> bf16
  k_f32_to_bf16<<<(M_ * H_ / 4) / 256, 256, 0, stream>>>(hidden, Xbf, M_ * H_ / 4);
  // 2. rope table
  k_rope_table<<<(S_ * 64) / 256, 256, 0, stream>>>(pos, tab);
  // 3. projections (naive, read original f32 weights)
  k_gemm_naive<<<dim3(H_ / 64,    M_ / 64), 256, 0, stream>>>(Xbf, wq, bq, Qw, nullptr, M_, H_,    H_);
  k_gemm_naive<<<dim3(NKVH_ / 64, M_ / 64), 256, 0, stream>>>(Xbf, wk, bk, Kw, nullptr, M_, NKVH_, H_);
  k_gemm_naive<<<dim3(NKVH_ / 64, M_ / 64), 256, 0, stream>>>(Xbf, wv, bv, Vw, nullptr, M_, NKVH_, H_);
  // 4. rope + caches (cache_k = f32 unrounded rotation; cache_v = f32 widened bf16)
  k_rope_q<<<(M_ * H_ / 4) / 256, 256, 0, stream>>>(Qw, tab);
  k_rope_k<<<(M_ * NKVH_ / 4) / 256, 256, 0, stream>>>(Kw, tab, cacheK);
  k_v_to_f32<<<(M_ * NKVH_ / 4) / 256, 256, 0, stream>>>(Vw, cacheV, M_ * NKVH_ / 4);
  // 5. NAIVE attention -> Ao (bf16; ref also rounds attn to bf16 before o-proj)
  k_attn_naive2<<<(S_ * NH_ * B_) / 4, 256, 0, stream>>>(Qw, Kw, Vw, Ao);
  // 6. output projection (naive, no bias) -> f32 out region
  k_gemm_naive<<<dim3(H_ / 64, M_ / 64), 256, 0, stream>>>(Ao, wo, nullptr, nullptr, outF, M_, H_, H_);
}

// Round 8
// 707.787 us; speedup vs baseline: 14.4380x; 14.4380x over previous
//
#include <hip/hip_runtime.h>
#include <hip/hip_bf16.h>
#include <math.h>

#define B_    2
#define S_    2048
#define H_    2048
#define NH_   16
#define NKV_  4
#define HD_   128
#define M_    (B_*S_)      // 4096
#define NKVH_ (NKV_*HD_)   // 512

typedef __bf16 bf16x8 __attribute__((ext_vector_type(8)));
typedef float  f32x4  __attribute__((ext_vector_type(4)));

__device__ __forceinline__ float bf2f(unsigned short u){
  unsigned int i = ((unsigned int)u) << 16; float f;
  __builtin_memcpy(&f, &i, 4); return f;
}
__device__ __forceinline__ unsigned short f2bf(float f){
  unsigned int i; __builtin_memcpy(&i, &f, 4);
  unsigned int r = (i + 0x7fffu + ((i >> 16) & 1u)) >> 16;
  return (unsigned short)r;
}

#define GLOAD_LDS16(g, l) __builtin_amdgcn_global_load_lds( \
    (const __attribute__((address_space(1))) void*)(g), \
    (__attribute__((address_space(3))) void*)(l), 16, 0, 0)

// ---------------- f32 -> bf16 bulk convert ----------------
__global__ void k_f32_to_bf16(const float* __restrict__ in, unsigned short* __restrict__ out, int n4){
  int idx = blockIdx.x * blockDim.x + threadIdx.x;
  if (idx >= n4) return;
  float4 v = reinterpret_cast<const float4*>(in)[idx];
  ushort4 o; o.x = f2bf(v.x); o.y = f2bf(v.y); o.z = f2bf(v.z); o.w = f2bf(v.w);
  reinterpret_cast<ushort4*>(out)[idx] = o;
}

// ---------------- W [K][N] f32 -> Wt [N][K] bf16 ----------------
__global__ void k_transpose_w(const float* __restrict__ W, unsigned short* __restrict__ Wt, int K, int N){
  __shared__ unsigned short tile[32][36];
  int t = threadIdx.x;
  int k0 = blockIdx.x * 32, n0 = blockIdx.y * 32;
  int kr = t >> 3, nc = (t & 7) * 4;
  float4 v = *reinterpret_cast<const float4*>(&W[(size_t)(k0 + kr) * N + n0 + nc]);
  tile[kr][nc+0] = f2bf(v.x); tile[kr][nc+1] = f2bf(v.y);
  tile[kr][nc+2] = f2bf(v.z); tile[kr][nc+3] = f2bf(v.w);
  __syncthreads();
  int nr = t >> 3, kc = (t & 7) * 4;
  ushort4 o;
  o.x = tile[kc+0][nr]; o.y = tile[kc+1][nr]; o.z = tile[kc+2][nr]; o.w = tile[kc+3][nr];
  *reinterpret_cast<ushort4*>(&Wt[(size_t)(n0 + nr) * K + k0 + kc]) = o;
}

// ---------------- V [b][s][c] bf16 -> Vt [b][c][s] bf16 ----------------
__global__ void k_transpose_v(const unsigned short* __restrict__ V, unsigned short* __restrict__ Vt){
  __shared__ unsigned short tile[32][36];
  int t = threadIdx.x;
  int s0 = blockIdx.x * 32, c0 = blockIdx.y * 32, b = blockIdx.z;
  int sr = t >> 3, cc = (t & 7) * 4;
  ushort4 v = *reinterpret_cast<const ushort4*>(&V[(size_t)(b * S_ + s0 + sr) * NKVH_ + c0 + cc]);
  tile[sr][cc+0] = v.x; tile[sr][cc+1] = v.y; tile[sr][cc+2] = v.z; tile[sr][cc+3] = v.w;
  __syncthreads();
  int cr = t >> 3, sc = (t & 7) * 4;
  ushort4 o;
  o.x = tile[sc+0][cr]; o.y = tile[sc+1][cr]; o.z = tile[sc+2][cr]; o.w = tile[sc+3][cr];
  *reinterpret_cast<ushort4*>(&Vt[(size_t)(b * NKVH_ + c0 + cr) * S_ + s0 + sc]) = o;
}

// ---------------- RoPE table ----------------
__global__ void k_rope_table(const int* __restrict__ pos, float2* __restrict__ tab){
  int idx = blockIdx.x * blockDim.x + threadIdx.x;
  if (idx >= S_ * 64) return;
  int s = idx >> 6, i = idx & 63;
  float p = (float)pos[s];
  float inv = expf(-(float)i * (13.815510557964274f / 64.0f));  // 1e6^(-i/64)
  float ang = p * inv;
  tab[idx] = make_float2(cosf(ang), sinf(ang));
}

// ---------------- RoPE in-place Q ----------------
__global__ void k_rope_q(unsigned short* __restrict__ Q, const float2* __restrict__ tab){
  int idx = blockIdx.x * blockDim.x + threadIdx.x;  // 2,097,152
  int row = idx >> 9;
  int col0 = (idx & 511) * 4;
  int s = row & (S_ - 1);
  int i0 = (col0 & (HD_ - 1)) >> 1;
  ushort4 v = reinterpret_cast<ushort4*>(Q)[idx];
  float2 t0 = tab[(s << 6) + i0], t1 = tab[(s << 6) + i0 + 1];
  float x0 = bf2f(v.x), x1 = bf2f(v.y), x2 = bf2f(v.z), x3 = bf2f(v.w);
  ushort4 o;
  o.x = f2bf(x0 * t0.x - x1 * t0.y);
  o.y = f2bf(x0 * t0.y + x1 * t0.x);
  o.z = f2bf(x2 * t1.x - x3 * t1.y);
  o.w = f2bf(x2 * t1.y + x3 * t1.x);
  reinterpret_cast<ushort4*>(Q)[idx] = o;
}

// ---- RoPE K: in-place bf16 + UNROUNDED f32 rotation -> cache_k (f32) ----
__global__ void k_rope_k(unsigned short* __restrict__ Kw, const float2* __restrict__ tab,
                         float* __restrict__ cacheK){
  int idx = blockIdx.x * blockDim.x + threadIdx.x;  // 524,288
  int row = idx >> 7;
  int col0 = (idx & 127) * 4;
  int s = row & (S_ - 1);
  int i0 = (col0 & (HD_ - 1)) >> 1;
  ushort4 v = reinterpret_cast<ushort4*>(Kw)[idx];
  float2 t0 = tab[(s << 6) + i0], t1 = tab[(s << 6) + i0 + 1];
  float x0 = bf2f(v.x), x1 = bf2f(v.y), x2 = bf2f(v.z), x3 = bf2f(v.w);
  float r0 = x0 * t0.x - x1 * t0.y;
  float r1 = x0 * t0.y + x1 * t0.x;
  float r2 = x2 * t1.x - x3 * t1.y;
  float r3 = x2 * t1.y + x3 * t1.x;
  ushort4 o; o.x = f2bf(r0); o.y = f2bf(r1); o.z = f2bf(r2); o.w = f2bf(r3);
  reinterpret_cast<ushort4*>(Kw)[idx] = o;
  float4 c; c.x = r0; c.y = r1; c.z = r2; c.w = r3;
  reinterpret_cast<float4*>(cacheK)[idx] = c;
}

// ---------------- V bf16 -> cache_v f32 ----------------
__global__ void k_v_to_f32(const unsigned short* __restrict__ in, float* __restrict__ out, int n4){
  int idx = blockIdx.x * blockDim.x + threadIdx.x;
  if (idx >= n4) return;
  ushort4 v = reinterpret_cast<const ushort4*>(in)[idx];
  float4 o; o.x = bf2f(v.x); o.y = bf2f(v.y); o.z = bf2f(v.z); o.w = bf2f(v.w);
  reinterpret_cast<float4*>(out)[idx] = o;
}

// ---------------- MFMA GEMM: C = A[M][K] * Bt[N][K]^T + bias ----------------
// 128x128 tile, BK=32, 4 waves, global_load_lds w=16 (m97 structure).
// Cf!=nullptr -> write bf16-rounded value widened to f32; else bf16 into Cb.
__global__ __launch_bounds__(256) void k_gemm_bt(
    const unsigned short* __restrict__ A,
    const unsigned short* __restrict__ Bt,
    const float* __restrict__ bias,
    unsigned short* __restrict__ Cb,
    float* __restrict__ Cf,
    int M, int N, int K)
{
  __shared__ unsigned short As[128 * 32];
  __shared__ unsigned short Bs[128 * 32];
  const int nbn = N >> 7;
  const int bm = blockIdx.x / nbn, bn = blockIdx.x % nbn;
  const int tid = threadIdx.x, lane = tid & 63, wave = tid >> 6;
  const int wr = wave >> 1, wc = wave & 1;
  const int gm0 = bm << 7, gn0 = bn << 7;
  const int l15 = lane & 15, lhi = lane >> 4;
  const int srow = lane >> 2, scol = (lane & 3) * 8;

  f32x4 acc[4][4];
  f32x4 zero = {0.f, 0.f, 0.f, 0.f};
  #pragma unroll
  for (int m = 0; m < 4; m++)
    #pragma unroll
    for (int n = 0; n < 4; n++) acc[m][n] = zero;

  for (int k0 = 0; k0 < K; k0 += 32) {
    __syncthreads();
    #pragma unroll
    for (int it = 0; it < 2; ++it) {
      int c = it * 4 + wave;
      const unsigned short* gA = A + (size_t)(gm0 + c * 16 + srow) * K + k0 + scol;
      GLOAD_LDS16(gA, As + c * 512);
      const unsigned short* gB = Bt + (size_t)(gn0 + c * 16 + srow) * K + k0 + scol;
      GLOAD_LDS16(gB, Bs + c * 512);
    }
    __syncthreads();
    bf16x8 af[4], bfr[4];
    #pragma unroll
    for (int m = 0; m < 4; m++)
      af[m] = *reinterpret_cast<const bf16x8*>(&As[(wr * 64 + m * 16 + l15) * 32 + lhi * 8]);
    #pragma unroll
    for (int n = 0; n < 4; n++)
      bfr[n] = *reinterpret_cast<const bf16x8*>(&Bs[(wc * 64 + n * 16 + l15) * 32 + lhi * 8]);
    #pragma unroll
    for (int m = 0; m < 4; m++)
      #pragma unroll
      for (int n = 0; n < 4; n++)
        acc[m][n] = __builtin_amdgcn_mfma_f32_16x16x32_bf16(af[m], bfr[n], acc[m][n], 0, 0, 0);
  }

  #pragma unroll
  for (int m = 0; m < 4; m++) {
    #pragma unroll
    for (int n = 0; n < 4; n++) {
      int col = gn0 + wc * 64 + n * 16 + l15;
      float bv = bias ? bias[col] : 0.0f;
      #pragma unroll
      for (int r = 0; r < 4; r++) {
        int row = gm0 + wr * 64 + m * 16 + lhi * 4 + r;
        size_t idx = (size_t)row * N + col;
        float v = acc[m][n][r] + bv;
        if (Cf) Cf[idx] = bf2f(f2bf(v));
        else    Cb[idx] = f2bf(v);
      }
    }
  }
}

// ---------------- MFMA flash attention, causal, GQA 4:1 ----------------
// grid (S/64, NH, B), 256 thr. wave -> 16 q rows. KT=32 k-tile, online softmax.
__global__ __launch_bounds__(256) void k_attn(
    const unsigned short* __restrict__ Q,   // [4096][2048]
    const unsigned short* __restrict__ K,   // [4096][512]
    const unsigned short* __restrict__ Vt,  // [B][4][128][2048]
    unsigned short* __restrict__ O)         // [4096][2048]
{
  __shared__ unsigned short Plds[4][16 * 32];
  const int qb = blockIdx.x, h = blockIdx.y, b = blockIdx.z;
  const int lane = threadIdx.x & 63, wave = threadIdx.x >> 6;
  const int l15 = lane & 15, lhi = lane >> 4;
  const int q0 = qb * 64 + wave * 16;
  const int kvh = h >> 2;
  const float scale = 0.08838834764831845f;  // 1/sqrt(128)

  bf16x8 qf[4];
  const unsigned short* qbase = Q + (size_t)(b * S_ + q0 + l15) * H_ + h * HD_ + lhi * 8;
  #pragma unroll
  for (int t = 0; t < 4; t++) qf[t] = *reinterpret_cast<const bf16x8*>(qbase + t * 32);

  f32x4 o[8];
  f32x4 zero = {0.f, 0.f, 0.f, 0.f};
  #pragma unroll
  for (int d = 0; d < 8; d++) o[d] = zero;
  float mrow[4] = {-1e30f, -1e30f, -1e30f, -1e30f};
  float lrow[4] = {0.f, 0.f, 0.f, 0.f};

  unsigned short* pl = &Plds[wave][0];
  const int ktmax = 2 * qb + 1;

  for (int kt = 0; kt <= ktmax; ++kt) {
    f32x4 sc[2];
    sc[0] = zero; sc[1] = zero;
    #pragma unroll
    for (int c = 0; c < 2; c++) {
      const unsigned short* kbase =
          K + (size_t)(b * S_ + kt * 32 + c * 16 + l15) * NKVH_ + kvh * HD_ + lhi * 8;
      #pragma unroll
      for (int t = 0; t < 4; t++) {
        bf16x8 kf = *reinterpret_cast<const bf16x8*>(kbase + t * 32);
        sc[c] = __builtin_amdgcn_mfma_f32_16x16x32_bf16(qf[t], kf, sc[c], 0, 0, 0);
      }
    }
    float p[2][4];
    #pragma unroll
    for (int r = 0; r < 4; r++) {
      int qi = q0 + lhi * 4 + r;
      float v0 = sc[0][r] * scale, v1 = sc[1][r] * scale;
      int k0i = kt * 32 + l15;
      if (k0i > qi) v0 = -1e30f;
      if (k0i + 16 > qi) v1 = -1e30f;
      float tm = fmaxf(v0, v1);
      #pragma unroll
      for (int msk = 1; msk < 16; msk <<= 1) tm = fmaxf(tm, __shfl_xor(tm, msk));
      float mnew = fmaxf(mrow[r], tm);
      float sscale = __expf(mrow[r] - mnew);
      float p0 = __expf(v0 - mnew), p1 = __expf(v1 - mnew);
      float psum = p0 + p1;
      #pragma unroll
      for (int msk = 1; msk < 16; msk <<= 1) psum += __shfl_xor(psum, msk);
      lrow[r] = lrow[r] * sscale + psum;
      mrow[r] = mnew;
      p[0][r] = p0; p[1][r] = p1;
      #pragma unroll
      for (int d = 0; d < 8; d++) o[d][r] *= sscale;
    }
    // cross-lane LDS round-trip: fence both sides (compiler reorder guard)
    #pragma unroll
    for (int c = 0; c < 2; c++)
      #pragma unroll
      for (int r = 0; r < 4; r++)
        pl[(lhi * 4 + r) * 32 + c * 16 + l15] = f2bf(p[c][r]);
    asm volatile("" ::: "memory");
    bf16x8 pf = *reinterpret_cast<const bf16x8*>(&pl[l15 * 32 + lhi * 8]);
    asm volatile("" ::: "memory");
    const unsigned short* vbase =
        Vt + (size_t)((b * NKV_ + kvh) * HD_ + l15) * S_ + kt * 32 + lhi * 8;
    #pragma unroll
    for (int d = 0; d < 8; d++) {
      bf16x8 vf = *reinterpret_cast<const bf16x8*>(vbase + (size_t)d * 16 * S_);
      o[d] = __builtin_amdgcn_mfma_f32_16x16x32_bf16(pf, vf, o[d], 0, 0, 0);
    }
  }

  #pragma unroll
  for (int r = 0; r < 4; r++) {
    float inv = 1.0f / lrow[r];
    size_t rowoff = (size_t)(b * S_ + q0 + lhi * 4 + r) * H_ + h * HD_;
    #pragma unroll
    for (int d = 0; d < 8; d++)
      O[rowoff + d * 16 + l15] = f2bf(o[d][r] * inv);
  }
}

// ---------------- launch ----------------
extern "C" void kernel_launch(void* const* d_in, const int* in_sizes, int n_in,
                              void* d_out, int out_size, void* d_ws, size_t ws_size,
                              hipStream_t stream) {
  const float* hidden = (const float*)d_in[0];
  const int*   pos    = (const int*)d_in[2];
  const float* wq     = (const float*)d_in[3];
  const float* bq     = (const float*)d_in[4];
  const float* wk     = (const float*)d_in[5];
  const float* bk     = (const float*)d_in[6];
  const float* wv     = (const float*)d_in[7];
  const float* bv     = (const float*)d_in[8];
  const float* wo     = (const float*)d_in[9];

  // d_out is FLOAT32: [ out 8.4M | cache_k 2.1M | cache_v 2.1M ]
  float* outF   = (float*)d_out;
  float* cacheK = outF + (size_t)M_ * H_;
  float* cacheV = cacheK + (size_t)M_ * NKVH_;

  char* w = (char*)d_ws;
  unsigned short* Xbf = (unsigned short*)w; w += (size_t)M_ * H_ * 2;      // 16.78 MB (reused as Ao)
  unsigned short* WqT = (unsigned short*)w; w += (size_t)H_ * H_ * 2;      //  8.39 MB
  unsigned short* WkT = (unsigned short*)w; w += (size_t)NKVH_ * H_ * 2;   //  2.10 MB
  unsigned short* WvT = (unsigned short*)w; w += (size_t)NKVH_ * H_ * 2;   //  2.10 MB
  unsigned short* WoT = (unsigned short*)w; w += (size_t)H_ * H_ * 2;      //  8.39 MB
  unsigned short* Qw  = (unsigned short*)w; w += (size_t)M_ * H_ * 2;      // 16.78 MB
  unsigned short* Kw  = (unsigned short*)w; w += (size_t)M_ * NKVH_ * 2;   //  4.19 MB
  unsigned short* Vw  = (unsigned short*)w; w += (size_t)M_ * NKVH_ * 2;   //  4.19 MB
  unsigned short* Vt  = (unsigned short*)w; w += (size_t)M_ * NKVH_ * 2;   //  4.19 MB
  float2*         tab = (float2*)w;         w += (size_t)S_ * 64 * sizeof(float2); // 1 MB
  unsigned short* Ao  = Xbf;  // alias: Xbf dead after QKV gemms

  // 1. hidden f32 -> bf16
  k_f32_to_bf16<<<(M_ * H_ / 4) / 256, 256, 0, stream>>>(hidden, Xbf, M_ * H_ / 4);
  // 2. weight transposes (f32 [K][N] -> bf16 [N][K])
  k_transpose_w<<<dim3(64, 64), 256, 0, stream>>>(wq, WqT, H_, H_);
  k_transpose_w<<<dim3(64, 16), 256, 0, stream>>>(wk, WkT, H_, NKVH_);
  k_transpose_w<<<dim3(64, 16), 256, 0, stream>>>(wv, WvT, H_, NKVH_);
  k_transpose_w<<<dim3(64, 64), 256, 0, stream>>>(wo, WoT, H_, H_);
  // 3. rope table
  k_rope_table<<<(S_ * 64) / 256, 256, 0, stream>>>(pos, tab);
  // 4. projections (MFMA)
  k_gemm_bt<<<32 * 16, 256, 0, stream>>>(Xbf, WqT, bq, Qw, nullptr, M_, H_, H_);
  k_gemm_bt<<<32 * 4,  256, 0, stream>>>(Xbf, WkT, bk, Kw, nullptr, M_, NKVH_, H_);
  k_gemm_bt<<<32 * 4,  256, 0, stream>>>(Xbf, WvT, bv, Vw, nullptr, M_, NKVH_, H_);
  // 5. rope + caches (cache_k f32 unrounded; cache_v f32 widened)
  k_rope_q<<<(M_ * H_ / 4) / 256, 256, 0, stream>>>(Qw, tab);
  k_rope_k<<<(M_ * NKVH_ / 4) / 256, 256, 0, stream>>>(Kw, tab, cacheK);
  k_v_to_f32<<<(M_ * NKVH_ / 4) / 256, 256, 0, stream>>>(Vw, cacheV, M_ * NKVH_ / 4);
  // 6. V transpose for PV B-operand
  k_transpose_v<<<dim3(S_ / 32, NKVH_ / 32, B_), 256, 0, stream>>>(Vw, Vt);
  // 7. MFMA flash attention
  k_attn<<<dim3(S_ / 64, NH_, B_), 256, 0, stream>>>(Qw, Kw, Vt, Ao);
  // 8. output projection -> f32 out
  k_gemm_bt<<<32 * 16, 256, 0, stream>>>(Ao, WoT, nullptr, nullptr, outF, M_, H_, H_);
}